// Round 8
// baseline (112.222 us; speedup 1.0000x reference)
//
#include <hip/hip_runtime.h>
#include <math.h>

#define NB 8
#define NH 3
#define NBH 24
#define NP 4096
#define BLK 256
#define RPB 128            // rows per block (2 wave-pairs x 64)
#define ROWBLKS (NP / RPB) // 32
#define CHALF (NP / 2)     // cols per wave (col-half split across wave pairs)

typedef _Float16 half4 __attribute__((ext_vector_type(4)));
typedef float floatx16 __attribute__((ext_vector_type(16)));

// Forced v_min3_f32: fuses the 3-input min AND forces MFMA results into VGPRs.
#define MIN3(r, a, b) asm("v_min3_f32 %0, %0, %1, %2" : "+v"(r) : "v"(a), "v"(b))

// out[0] = 25 * sum_b || N_b N_b^T - I ||_F  (plain store; runs before chamfer adds)
__global__ void reg_kernel(const float* __restrict__ planes, float* __restrict__ out) {
    const int l = threadIdx.x;
    float r = 0.0f;
    if (l < NB) {
        float n[NH][3];
        for (int hh = 0; hh < NH; ++hh) {
            const float* pl = planes + (l * NH + hh) * 4;
            float a0 = pl[0], a1 = pl[1], a2 = pl[2];
            float inv = 1.0f / sqrtf(a0 * a0 + a1 * a1 + a2 * a2);
            n[hh][0] = a0 * inv; n[hh][1] = a1 * inv; n[hh][2] = a2 * inv;
        }
        float fro = 0.0f;
        for (int i = 0; i < NH; ++i)
            for (int j = 0; j < NH; ++j) {
                float d = n[i][0] * n[j][0] + n[i][1] * n[j][1] + n[i][2] * n[j][2]
                          - (i == j ? 1.0f : 0.0f);
                fro += d * d;
            }
        r = 25.0f * sqrtf(fro);
    }
    for (int o = 32; o; o >>= 1) r += __shfl_down(r, o);
    if (l == 0) out[0] = r;
}

// K=8 MFMA: D = A(32x8)*B(8x32) + C. A row = [r0,r1,r2,1] (lanes<32; lanes>=32
// hold k=4..7 = ZEROS, so B's k>=4 junk — the broadcast duplicate of the col
// data — is annihilated). B = raw ds_read_b64 of [-2c0,-2c1,-2c2,csq]: zero
// assembly movs. Each wave: 2 A-frags (64 rows) x its col-half (2048 cols);
// per 2 col-tiles: 2 ds_read_b64 + 4 MFMA + 32 v_min3 (the VALU floor).
// Wave-pairs combine partial row-mins via 128 B of LDS; clamp after full min.
__global__ void __launch_bounds__(BLK, 3) chamfer_mfma(const float* __restrict__ pts,
                                                       const float* __restrict__ planes,
                                                       float* __restrict__ out) {
    __shared__ _Float16 qcols[NP * 4];     // 32 KB: per col [-2c0,-2c1,-2c2,csq]
    __shared__ float rsqbuf[RPB];
    __shared__ float comb[2][2][2][16];    // [pair][h][frag][j]

    const int tid    = threadIdx.x;
    const int lane   = tid & 63;
    const int wave   = tid >> 6;
    const int pairid = wave >> 1;          // row group (0: rows 0-63, 1: 64-127)
    const int cw     = wave & 1;           // col half
    const int h      = lane >> 5;
    const int bh     = blockIdx.y;
    const int b      = bh / NH;

    const float* pl = planes + bh * 4;
    float n0 = pl[0], n1 = pl[1], n2 = pl[2], off = pl[3];
    float inv = 1.0f / sqrtf(n0 * n0 + n1 * n1 + n2 * n2);
    n0 *= inv; n1 *= inv; n2 *= inv;

    const float* bp = pts + (size_t)b * NP * 3;
    const float scale = 1.0f / (float)(NB * NP);

    for (int dir = 0; dir < 2; ++dir) {
        __syncthreads();   // qcols/comb safe to overwrite

        // stage 4096 cols (reflected when dir==0)
        for (int i = tid; i < NP; i += BLK) {
            float y0 = bp[i * 3 + 0], y1 = bp[i * 3 + 1], y2 = bp[i * 3 + 2];
            if (!dir) { float t = 2.0f * (n0 * y0 + n1 * y1 + n2 * y2 + off); y0 -= t * n0; y1 -= t * n1; y2 -= t * n2; }
            float csq = y0 * y0 + y1 * y1 + y2 * y2;
            half4 v = { (_Float16)(-2.0f * y0), (_Float16)(-2.0f * y1),
                        (_Float16)(-2.0f * y2), (_Float16)csq };
            *(half4*)&qcols[i * 4] = v;
        }

        // A fragments: 2 x 32 rows per wave (reflected when dir==1)
        const int r0 = blockIdx.x * RPB + pairid * 64 + (lane & 31);
        half4 A0 = {0, 0, 0, 0}, A1 = {0, 0, 0, 0};
        {
            float a0 = bp[r0 * 3 + 0], a1 = bp[r0 * 3 + 1], a2 = bp[r0 * 3 + 2];
            float b0 = bp[(r0 + 32) * 3 + 0], b1 = bp[(r0 + 32) * 3 + 1], b2 = bp[(r0 + 32) * 3 + 2];
            if (dir) {
                float t = 2.0f * (n0 * a0 + n1 * a1 + n2 * a2 + off);
                a0 -= t * n0; a1 -= t * n1; a2 -= t * n2;
                float u = 2.0f * (n0 * b0 + n1 * b1 + n2 * b2 + off);
                b0 -= u * n0; b1 -= u * n1; b2 -= u * n2;
            }
            if (lane < 32) {
                rsqbuf[pairid * 64 + (lane & 31)]      = a0 * a0 + a1 * a1 + a2 * a2;
                rsqbuf[pairid * 64 + 32 + (lane & 31)] = b0 * b0 + b1 * b1 + b2 * b2;
                A0[0] = (_Float16)a0; A0[1] = (_Float16)a1; A0[2] = (_Float16)a2; A0[3] = (_Float16)1.0f;
                A1[0] = (_Float16)b0; A1[1] = (_Float16)b1; A1[2] = (_Float16)b2; A1[3] = (_Float16)1.0f;
            }
        }
        __syncthreads();

        // C fragments: rsq per output row (C/D: col=lane&31, row=(j&3)+8*(j>>2)+4*h)
        floatx16 crsq0, crsq1;
        #pragma unroll
        for (int j = 0; j < 16; ++j) {
            int rr = (j & 3) + 8 * (j >> 2) + 4 * h;
            crsq0[j] = rsqbuf[pairid * 64 + rr];
            crsq1[j] = rsqbuf[pairid * 64 + 32 + rr];
        }

        float rm0[16], rm1[16];
        #pragma unroll
        for (int j = 0; j < 16; ++j) { rm0[j] = 1e30f; rm1[j] = 1e30f; }

        // this wave's col-half: 2048 cols = 64 tiles of 32; 2 tiles per iter
        const _Float16* bcol = &qcols[(cw * CHALF + (lane & 31)) * 4];

        half4 c0 = *(const half4*)(bcol);
        half4 c1 = *(const half4*)(bcol + 128);
        #pragma unroll 1
        for (int t = 0; t < 62; t += 2) {
            floatx16 d00 = __builtin_amdgcn_mfma_f32_32x32x8f16(A0, c0, crsq0, 0, 0, 0);
            floatx16 d10 = __builtin_amdgcn_mfma_f32_32x32x8f16(A1, c0, crsq1, 0, 0, 0);
            floatx16 d01 = __builtin_amdgcn_mfma_f32_32x32x8f16(A0, c1, crsq0, 0, 0, 0);
            floatx16 d11 = __builtin_amdgcn_mfma_f32_32x32x8f16(A1, c1, crsq1, 0, 0, 0);
            c0 = *(const half4*)(bcol + (t + 2) * 128);   // prefetch next tile pair
            c1 = *(const half4*)(bcol + (t + 3) * 128);
            #pragma unroll
            for (int j = 0; j < 16; ++j) MIN3(rm0[j], d00[j], d01[j]);
            #pragma unroll
            for (int j = 0; j < 16; ++j) MIN3(rm1[j], d10[j], d11[j]);
        }
        {   // peeled last pair
            floatx16 d00 = __builtin_amdgcn_mfma_f32_32x32x8f16(A0, c0, crsq0, 0, 0, 0);
            floatx16 d10 = __builtin_amdgcn_mfma_f32_32x32x8f16(A1, c0, crsq1, 0, 0, 0);
            floatx16 d01 = __builtin_amdgcn_mfma_f32_32x32x8f16(A0, c1, crsq0, 0, 0, 0);
            floatx16 d11 = __builtin_amdgcn_mfma_f32_32x32x8f16(A1, c1, crsq1, 0, 0, 0);
            #pragma unroll
            for (int j = 0; j < 16; ++j) MIN3(rm0[j], d00[j], d01[j]);
            #pragma unroll
            for (int j = 0; j < 16; ++j) MIN3(rm1[j], d10[j], d11[j]);
        }

        // butterfly: complete min over the 32 lanes sharing each row
        #pragma unroll
        for (int j = 0; j < 16; ++j) {
            float v = rm0[j], w = rm1[j];
            v = fminf(v, __shfl_xor(v, 1));  w = fminf(w, __shfl_xor(w, 1));
            v = fminf(v, __shfl_xor(v, 2));  w = fminf(w, __shfl_xor(w, 2));
            v = fminf(v, __shfl_xor(v, 4));  w = fminf(w, __shfl_xor(w, 4));
            v = fminf(v, __shfl_xor(v, 8));  w = fminf(w, __shfl_xor(w, 8));
            v = fminf(v, __shfl_xor(v, 16)); w = fminf(w, __shfl_xor(w, 16));
            rm0[j] = v; rm1[j] = w;
        }

        // wave-pair combine: odd wave (other col-half) publishes, even wave reduces
        if (cw) {
            if ((lane & 31) == 0) {
                #pragma unroll
                for (int j = 0; j < 16; ++j) {
                    comb[pairid][h][0][j] = rm0[j];
                    comb[pairid][h][1][j] = rm1[j];
                }
            }
        }
        __syncthreads();
        if (!cw) {
            float s = 0.0f;
            #pragma unroll
            for (int j = 0; j < 16; ++j) {
                s += fmaxf(fminf(rm0[j], comb[pairid][h][0][j]), 0.0f);
                s += fmaxf(fminf(rm1[j], comb[pairid][h][1][j]), 0.0f);
            }
            s += __shfl_xor(s, 32);   // combine the two 16-row halves
            if (lane == 0) atomicAdd(out, s * scale);
        }
    }
}

extern "C" void kernel_launch(void* const* d_in, const int* in_sizes, int n_in,
                              void* d_out, int out_size, void* d_ws, size_t ws_size,
                              hipStream_t stream) {
    const float* planes = (const float*)d_in[0];  // (8,3,4) fp32
    const float* pts    = (const float*)d_in[1];  // (8,4096,3) fp32
    float* out          = (float*)d_out;

    reg_kernel<<<1, 64, 0, stream>>>(planes, out);   // initializes out[0]

    dim3 grid(ROWBLKS, NBH);
    chamfer_mfma<<<grid, BLK, 0, stream>>>(pts, planes, out);
}

// Round 9
// 94.306 us; speedup vs baseline: 1.1900x; 1.1900x over previous
//
#include <hip/hip_runtime.h>
#include <math.h>

#define NB 8
#define NH 3
#define NBH 24
#define NP 4096
#define BLK 256
#define RPB 128            // rows per block (4 waves x 32)
#define ROWBLKS (NP / RPB) // 32

typedef _Float16 half4 __attribute__((ext_vector_type(4)));
typedef float floatx16 __attribute__((ext_vector_type(16)));

// Forced v_min3_f32 (3-input min; no -ffast-math so compiler won't fuse).
#define MIN3(r, a, b) asm("v_min3_f32 %0, %0, %1, %2" : "+v"(r) : "v"(a), "v"(b))

// MFMA via inline asm, all operands constrained to VGPRs ("v"/"=&v"): the RA
// cannot park D in AGPRs, so the ~32 v_accvgpr_read copies/iter (R6-R8's
// hidden 11 us of VALU) are impossible by construction. K=8 shape: A,B are
// 2-VGPR (half4) so B is the RAW ds_read_b64 payload (no assembly movs);
// lanes>=32 hold A-zeros (k=4..7) which annihilate B's junk there.
#define MFMA8(d, a, bb, c) \
    asm("v_mfma_f32_32x32x8_f16 %0, %1, %2, %3" : "=&v"(d) : "v"(a), "v"(bb), "v"(c))

// out[0] = 25 * sum_b || N_b N_b^T - I ||_F  (plain store; runs before chamfer adds)
__global__ void reg_kernel(const float* __restrict__ planes, float* __restrict__ out) {
    const int l = threadIdx.x;
    float r = 0.0f;
    if (l < NB) {
        float n[NH][3];
        for (int hh = 0; hh < NH; ++hh) {
            const float* pl = planes + (l * NH + hh) * 4;
            float a0 = pl[0], a1 = pl[1], a2 = pl[2];
            float inv = 1.0f / sqrtf(a0 * a0 + a1 * a1 + a2 * a2);
            n[hh][0] = a0 * inv; n[hh][1] = a1 * inv; n[hh][2] = a2 * inv;
        }
        float fro = 0.0f;
        for (int i = 0; i < NH; ++i)
            for (int j = 0; j < NH; ++j) {
                float d = n[i][0] * n[j][0] + n[i][1] * n[j][1] + n[i][2] * n[j][2]
                          - (i == j ? 1.0f : 0.0f);
                fro += d * d;
            }
        r = 25.0f * sqrtf(fro);
    }
    for (int o = 32; o; o >>= 1) r += __shfl_down(r, o);
    if (l == 0) out[0] = r;
}

// D = A(32x8)*B(8x32) + C, K=4 real: A row = [r0,r1,r2,1] (lanes<32, zeros
// elsewhere); B col = raw [-2c0,-2c1,-2c2,csq]; C = rsq(row) -> D = full
// squared distance. Row-min via v_min3; clamp after min (exact); block-reduce;
// one atomicAdd per block. dir folded into a block loop: grid 768 = 3 blk/CU.
__global__ void __launch_bounds__(BLK, 3) chamfer_mfma(const float* __restrict__ pts,
                                                       const float* __restrict__ planes,
                                                       float* __restrict__ out) {
    __shared__ _Float16 qcols[NP * 4];   // 32 KB: per col [-2c0,-2c1,-2c2,csq]
    __shared__ float rsqbuf[RPB];
    __shared__ float bsum[4];

    const int tid  = threadIdx.x;
    const int lane = tid & 63;
    const int wave = tid >> 6;
    const int bh   = blockIdx.y;
    const int b    = bh / NH;

    const float* pl = planes + bh * 4;
    float n0 = pl[0], n1 = pl[1], n2 = pl[2], off = pl[3];
    float inv = 1.0f / sqrtf(n0 * n0 + n1 * n1 + n2 * n2);
    n0 *= inv; n1 *= inv; n2 *= inv;

    const float* bp = pts + (size_t)b * NP * 3;
    const int h = lane >> 5;

    float total = 0.0f;

    for (int dir = 0; dir < 2; ++dir) {
        // stage 4096 cols (reflected when dir==0)
        for (int i = tid; i < NP; i += BLK) {
            float y0 = bp[i * 3 + 0], y1 = bp[i * 3 + 1], y2 = bp[i * 3 + 2];
            if (!dir) { float t = 2.0f * (n0 * y0 + n1 * y1 + n2 * y2 + off); y0 -= t * n0; y1 -= t * n1; y2 -= t * n2; }
            float csq = y0 * y0 + y1 * y1 + y2 * y2;
            half4 v = { (_Float16)(-2.0f * y0), (_Float16)(-2.0f * y1),
                        (_Float16)(-2.0f * y2), (_Float16)csq };
            *(half4*)&qcols[i * 4] = v;
        }

        // A fragment: lane m = lane&31 (k = 4*h + j); only lanes<32 real
        const int rlocal = wave * 32 + (lane & 31);
        const int row = blockIdx.x * RPB + rlocal;
        half4 afrag = {0, 0, 0, 0};
        {
            float a0 = bp[row * 3 + 0], a1 = bp[row * 3 + 1], a2 = bp[row * 3 + 2];
            if (dir) { float t = 2.0f * (n0 * a0 + n1 * a1 + n2 * a2 + off); a0 -= t * n0; a1 -= t * n1; a2 -= t * n2; }
            if (lane < 32) {
                rsqbuf[rlocal] = a0 * a0 + a1 * a1 + a2 * a2;
                afrag[0] = (_Float16)a0; afrag[1] = (_Float16)a1;
                afrag[2] = (_Float16)a2; afrag[3] = (_Float16)1.0f;
            }
        }
        __syncthreads();

        // C fragment: rsq per output row (C/D: col=lane&31, row=(j&3)+8*(j>>2)+4*h)
        floatx16 crsq;
        #pragma unroll
        for (int j = 0; j < 16; ++j)
            crsq[j] = rsqbuf[wave * 32 + (j & 3) + 8 * (j >> 2) + 4 * h];

        float rm[16];
        #pragma unroll
        for (int j = 0; j < 16; ++j) rm[j] = 1e30f;

        // B: lane covers cols ≡ (lane&31) mod 32 (lanes 32-63 broadcast dup)
        const _Float16* bcol = &qcols[(lane & 31) * 4];

        half4 c0 = *(const half4*)(bcol);
        half4 c1 = *(const half4*)(bcol + 128);
        #pragma unroll 1
        for (int t = 0; t < 126; t += 2) {
            floatx16 d0, d1;
            MFMA8(d0, afrag, c0, crsq);
            MFMA8(d1, afrag, c1, crsq);
            c0 = *(const half4*)(bcol + (t + 2) * 128);   // prefetch next pair
            c1 = *(const half4*)(bcol + (t + 3) * 128);
            #pragma unroll
            for (int j = 0; j < 16; ++j)
                MIN3(rm[j], d0[j], d1[j]);
        }
        {   // peeled last iteration
            floatx16 d0, d1;
            MFMA8(d0, afrag, c0, crsq);
            MFMA8(d1, afrag, c1, crsq);
            #pragma unroll
            for (int j = 0; j < 16; ++j)
                MIN3(rm[j], d0[j], d1[j]);
        }

        // min across the 32 lanes sharing each row, then clamp + sum
        #pragma unroll
        for (int j = 0; j < 16; ++j) {
            float v = rm[j];
            v = fminf(v, __shfl_xor(v, 1));
            v = fminf(v, __shfl_xor(v, 2));
            v = fminf(v, __shfl_xor(v, 4));
            v = fminf(v, __shfl_xor(v, 8));
            v = fminf(v, __shfl_xor(v, 16));
            rm[j] = v;
        }
        float s = 0.0f;
        #pragma unroll
        for (int j = 0; j < 16; ++j) s += fmaxf(rm[j], 0.0f);  // clamp after min
        s += __shfl_xor(s, 32);   // combine the two 16-row halves of the wave
        total += s;

        __syncthreads();   // qcols/rsqbuf safe to overwrite for next dir
    }

    if (lane == 0) bsum[wave] = total;
    __syncthreads();
    if (tid == 0)
        atomicAdd(out, (bsum[0] + bsum[1] + bsum[2] + bsum[3]) * (1.0f / (float)(NB * NP)));
}

extern "C" void kernel_launch(void* const* d_in, const int* in_sizes, int n_in,
                              void* d_out, int out_size, void* d_ws, size_t ws_size,
                              hipStream_t stream) {
    const float* planes = (const float*)d_in[0];  // (8,3,4) fp32
    const float* pts    = (const float*)d_in[1];  // (8,4096,3) fp32
    float* out          = (float*)d_out;

    reg_kernel<<<1, 64, 0, stream>>>(planes, out);   // initializes out[0]

    dim3 grid(ROWBLKS, NBH);
    chamfer_mfma<<<grid, BLK, 0, stream>>>(pts, planes, out);
}

// Round 10
// 93.228 us; speedup vs baseline: 1.2037x; 1.0116x over previous
//
#include <hip/hip_runtime.h>
#include <math.h>

#define NB 8
#define NH 3
#define NBH 24
#define NP 4096
#define BLK 256
#define RPB 128            // rows per block (4 waves x 32)
#define ROWBLKS (NP / RPB) // 32

typedef _Float16 half4 __attribute__((ext_vector_type(4)));
typedef _Float16 half8 __attribute__((ext_vector_type(8)));
typedef float floatx16 __attribute__((ext_vector_type(16)));

// Forced v_min3_f32 (3-input min; no -ffast-math so compiler won't fuse).
#define MIN3(r, a, b) asm("v_min3_f32 %0, %0, %1, %2" : "+v"(r) : "v"(a), "v"(b))

// MFMA via inline asm, all-VGPR constraints (no AGPR parking possible).
// K=8 f16 shape: A,B are 2-VGPR (half4); B comes straight from LDS.
#define MFMA8(d, a, bb, c) \
    asm("v_mfma_f32_32x32x8_f16 %0, %1, %2, %3" : "=&v"(d) : "v"(a), "v"(bb), "v"(c))

// even / odd columns of a b128 supertile load (cols 2l, 2l+1)
#define LO4(c8) __builtin_shufflevector(c8, c8, 0, 1, 2, 3)
#define HI4(c8) __builtin_shufflevector(c8, c8, 4, 5, 6, 7)

// out[0] = 25 * sum_b || N_b N_b^T - I ||_F  (plain store; runs before chamfer adds)
__global__ void reg_kernel(const float* __restrict__ planes, float* __restrict__ out) {
    const int l = threadIdx.x;
    float r = 0.0f;
    if (l < NB) {
        float n[NH][3];
        for (int hh = 0; hh < NH; ++hh) {
            const float* pl = planes + (l * NH + hh) * 4;
            float a0 = pl[0], a1 = pl[1], a2 = pl[2];
            float inv = 1.0f / sqrtf(a0 * a0 + a1 * a1 + a2 * a2);
            n[hh][0] = a0 * inv; n[hh][1] = a1 * inv; n[hh][2] = a2 * inv;
        }
        float fro = 0.0f;
        for (int i = 0; i < NH; ++i)
            for (int j = 0; j < NH; ++j) {
                float d = n[i][0] * n[j][0] + n[i][1] * n[j][1] + n[i][2] * n[j][2]
                          - (i == j ? 1.0f : 0.0f);
                fro += d * d;
            }
        r = 25.0f * sqrtf(fro);
    }
    for (int o = 32; o; o >>= 1) r += __shfl_down(r, o);
    if (l == 0) out[0] = r;
}

// D = A(32x8)*B(8x32) + C, K=4 real: A row = [r0,r1,r2,1] (lanes<32, zeros
// elsewhere annihilate B's k>=4 lanes); B col = raw [-2c0,-2c1,-2c2,csq];
// C = rsq(row) -> D = full squared distance. Columns fed as 64-col supertiles
// (1 ds_read_b128/lane = cols 2l,2l+1; even/odd split — min is permutation-
// invariant). 2-deep dA/dB ping-pong: next supertile's MFMAs issue BEFORE
// this one's min3 consumption, covering the ~18-cyc MFMA result latency.
__global__ void __launch_bounds__(BLK, 3) chamfer_mfma(const float* __restrict__ pts,
                                                       const float* __restrict__ planes,
                                                       float* __restrict__ out) {
    __shared__ _Float16 qcols[NP * 4];   // 32 KB: per col [-2c0,-2c1,-2c2,csq]
    __shared__ float rsqbuf[RPB];
    __shared__ float bsum[4];

    const int tid  = threadIdx.x;
    const int lane = tid & 63;
    const int wave = tid >> 6;
    const int bh   = blockIdx.y;
    const int b    = bh / NH;

    const float* pl = planes + bh * 4;
    float n0 = pl[0], n1 = pl[1], n2 = pl[2], off = pl[3];
    float inv = 1.0f / sqrtf(n0 * n0 + n1 * n1 + n2 * n2);
    n0 *= inv; n1 *= inv; n2 *= inv;

    const float* bp = pts + (size_t)b * NP * 3;
    const int h = lane >> 5;

    float total = 0.0f;

    for (int dir = 0; dir < 2; ++dir) {
        // stage 4096 cols (reflected when dir==0)
        for (int i = tid; i < NP; i += BLK) {
            float y0 = bp[i * 3 + 0], y1 = bp[i * 3 + 1], y2 = bp[i * 3 + 2];
            if (!dir) { float t = 2.0f * (n0 * y0 + n1 * y1 + n2 * y2 + off); y0 -= t * n0; y1 -= t * n1; y2 -= t * n2; }
            float csq = y0 * y0 + y1 * y1 + y2 * y2;
            half4 v = { (_Float16)(-2.0f * y0), (_Float16)(-2.0f * y1),
                        (_Float16)(-2.0f * y2), (_Float16)csq };
            *(half4*)&qcols[i * 4] = v;
        }

        // A fragment: lane m = lane&31 (k = 4*h + j); only lanes<32 real
        const int rlocal = wave * 32 + (lane & 31);
        const int row = blockIdx.x * RPB + rlocal;
        half4 afrag = {0, 0, 0, 0};
        {
            float a0 = bp[row * 3 + 0], a1 = bp[row * 3 + 1], a2 = bp[row * 3 + 2];
            if (dir) { float t = 2.0f * (n0 * a0 + n1 * a1 + n2 * a2 + off); a0 -= t * n0; a1 -= t * n1; a2 -= t * n2; }
            if (lane < 32) {
                rsqbuf[rlocal] = a0 * a0 + a1 * a1 + a2 * a2;
                afrag[0] = (_Float16)a0; afrag[1] = (_Float16)a1;
                afrag[2] = (_Float16)a2; afrag[3] = (_Float16)1.0f;
            }
        }
        __syncthreads();

        // C fragment: rsq per output row (C/D: col=lane&31, row=(j&3)+8*(j>>2)+4*h)
        floatx16 crsq;
        #pragma unroll
        for (int j = 0; j < 16; ++j)
            crsq[j] = rsqbuf[wave * 32 + (j & 3) + 8 * (j >> 2) + 4 * h];

        float rm[16];
        #pragma unroll
        for (int j = 0; j < 16; ++j) rm[j] = 1e30f;

        // supertile u (64 cols): lane reads cols u*64 + {2l, 2l+1} via b128
        const _Float16* bcol = &qcols[(lane & 31) * 8];

        half8 cc0 = *(const half8*)(bcol);         // st 0
        half8 cc1 = *(const half8*)(bcol + 256);   // st 1
        floatx16 dA0, dA1, dB0, dB1;
        MFMA8(dA0, afrag, LO4(cc0), crsq);         // st 0
        MFMA8(dA1, afrag, HI4(cc0), crsq);

        #pragma unroll 1
        for (int u = 2; u < 64; u += 2) {
            half8 nc0 = *(const half8*)(bcol + u * 256);         // prefetch st u
            MFMA8(dB0, afrag, LO4(cc1), crsq);                   // st u-1
            MFMA8(dB1, afrag, HI4(cc1), crsq);
            #pragma unroll
            for (int j = 0; j < 16; ++j) MIN3(rm[j], dA0[j], dA1[j]);   // st u-2
            half8 nc1 = *(const half8*)(bcol + (u + 1) * 256);   // prefetch st u+1
            MFMA8(dA0, afrag, LO4(nc0), crsq);                   // st u
            MFMA8(dA1, afrag, HI4(nc0), crsq);
            #pragma unroll
            for (int j = 0; j < 16; ++j) MIN3(rm[j], dB0[j], dB1[j]);   // st u-1
            cc1 = nc1;
        }
        {   // epilogue: st 63 MFMAs, consume st 62 + st 63
            MFMA8(dB0, afrag, LO4(cc1), crsq);
            MFMA8(dB1, afrag, HI4(cc1), crsq);
            #pragma unroll
            for (int j = 0; j < 16; ++j) MIN3(rm[j], dA0[j], dA1[j]);
            #pragma unroll
            for (int j = 0; j < 16; ++j) MIN3(rm[j], dB0[j], dB1[j]);
        }

        // min across the 32 lanes sharing each row, then clamp + sum
        #pragma unroll
        for (int j = 0; j < 16; ++j) {
            float v = rm[j];
            v = fminf(v, __shfl_xor(v, 1));
            v = fminf(v, __shfl_xor(v, 2));
            v = fminf(v, __shfl_xor(v, 4));
            v = fminf(v, __shfl_xor(v, 8));
            v = fminf(v, __shfl_xor(v, 16));
            rm[j] = v;
        }
        float s = 0.0f;
        #pragma unroll
        for (int j = 0; j < 16; ++j) s += fmaxf(rm[j], 0.0f);  // clamp after min
        s += __shfl_xor(s, 32);   // combine the two 16-row halves of the wave
        total += s;

        __syncthreads();   // qcols/rsqbuf safe to overwrite for next dir
    }

    if (lane == 0) bsum[wave] = total;
    __syncthreads();
    if (tid == 0)
        atomicAdd(out, (bsum[0] + bsum[1] + bsum[2] + bsum[3]) * (1.0f / (float)(NB * NP)));
}

extern "C" void kernel_launch(void* const* d_in, const int* in_sizes, int n_in,
                              void* d_out, int out_size, void* d_ws, size_t ws_size,
                              hipStream_t stream) {
    const float* planes = (const float*)d_in[0];  // (8,3,4) fp32
    const float* pts    = (const float*)d_in[1];  // (8,4096,3) fp32
    float* out          = (float*)d_out;

    reg_kernel<<<1, 64, 0, stream>>>(planes, out);   // initializes out[0]

    dim3 grid(ROWBLKS, NBH);
    chamfer_mfma<<<grid, BLK, 0, stream>>>(pts, planes, out);
}

// Round 11
// 91.395 us; speedup vs baseline: 1.2279x; 1.0201x over previous
//
#include <hip/hip_runtime.h>
#include <math.h>

#define NB 8
#define NH 3
#define NBH 24
#define NP 4096
#define BLK 256
#define RPB 128            // rows per block (4 waves x 32)
#define ROWBLKS (NP / RPB) // 32

typedef _Float16 half8 __attribute__((ext_vector_type(8)));
typedef float floatx16 __attribute__((ext_vector_type(16)));

// Forced v_min3_f32 (3-input min; no -ffast-math so compiler won't fuse).
#define MIN3(r, a, b) asm("v_min3_f32 %0, %0, %1, %2" : "+v"(r) : "v"(a), "v"(b))

// Native gfx950 x16 MFMA via inline asm, all-VGPR (no AGPR parking).
// A,B = 4 VGPRs (half8), D = 16 VGPRs.
#define MFMA16(d, a, bb, c) \
    asm("v_mfma_f32_32x32x16_f16 %0, %1, %2, %3" : "=&v"(d) : "v"(a), "v"(bb), "v"(c))

// out[0] = 25 * sum_b || N_b N_b^T - I ||_F  (plain store; runs before chamfer adds)
__global__ void reg_kernel(const float* __restrict__ planes, float* __restrict__ out) {
    const int l = threadIdx.x;
    float r = 0.0f;
    if (l < NB) {
        float n[NH][3];
        for (int hh = 0; hh < NH; ++hh) {
            const float* pl = planes + (l * NH + hh) * 4;
            float a0 = pl[0], a1 = pl[1], a2 = pl[2];
            float inv = 1.0f / sqrtf(a0 * a0 + a1 * a1 + a2 * a2);
            n[hh][0] = a0 * inv; n[hh][1] = a1 * inv; n[hh][2] = a2 * inv;
        }
        float fro = 0.0f;
        for (int i = 0; i < NH; ++i)
            for (int j = 0; j < NH; ++j) {
                float d = n[i][0] * n[j][0] + n[i][1] * n[j][1] + n[i][2] * n[j][2]
                          - (i == j ? 1.0f : 0.0f);
                fro += d * d;
            }
        r = 25.0f * sqrtf(fro);
    }
    for (int o = 32; o; o >>= 1) r += __shfl_down(r, o);
    if (l == 0) out[0] = r;
}

// Native 32x32x16: B = RAW ds_read_b128 payload = two packed columns
// (k=0..3 even col, k=4..7 odd col of a 64-col supertile). A_even holds
// [r0,r1,r2,1] in k=0..3 (zeros k=4..7), A_odd the reverse — each MFMA's
// A-zeros annihilate the other packed column. Zero B-assembly movs.
// 4-buffer pipeline: loads run ~2 lines (~80 cyc) ahead of their MFMA;
// min3 consumes results ~2 lines after issue. C = rsq(row) so D = full
// squared distance; clamp after min (exact); block-reduce; 1 atomic/block.
__global__ void __launch_bounds__(BLK, 3) chamfer_mfma(const float* __restrict__ pts,
                                                       const float* __restrict__ planes,
                                                       float* __restrict__ out) {
    __shared__ _Float16 qcols[NP * 4];   // 32 KB: per col [-2c0,-2c1,-2c2,csq]
    __shared__ float rsqbuf[RPB];
    __shared__ float bsum[4];

    const int tid  = threadIdx.x;
    const int lane = tid & 63;
    const int wave = tid >> 6;
    const int bh   = blockIdx.y;
    const int b    = bh / NH;

    const float* pl = planes + bh * 4;
    float n0 = pl[0], n1 = pl[1], n2 = pl[2], off = pl[3];
    float inv = 1.0f / sqrtf(n0 * n0 + n1 * n1 + n2 * n2);
    n0 *= inv; n1 *= inv; n2 *= inv;

    const float* bp = pts + (size_t)b * NP * 3;
    const int h = lane >> 5;

    float total = 0.0f;

    for (int dir = 0; dir < 2; ++dir) {
        // stage 4096 cols (reflected when dir==0)
        for (int i = tid; i < NP; i += BLK) {
            float y0 = bp[i * 3 + 0], y1 = bp[i * 3 + 1], y2 = bp[i * 3 + 2];
            if (!dir) { float t = 2.0f * (n0 * y0 + n1 * y1 + n2 * y2 + off); y0 -= t * n0; y1 -= t * n1; y2 -= t * n2; }
            float csq = y0 * y0 + y1 * y1 + y2 * y2;
            _Float16* q = &qcols[i * 4];
            q[0] = (_Float16)(-2.0f * y0); q[1] = (_Float16)(-2.0f * y1);
            q[2] = (_Float16)(-2.0f * y2); q[3] = (_Float16)csq;
        }

        // A fragments: lane m = lane&31; only lanes<32 carry data.
        // A_even: k=0..3 = [r,1]; A_odd: k=4..7 = [r,1]; all else zero.
        const int rlocal = wave * 32 + (lane & 31);
        const int row = blockIdx.x * RPB + rlocal;
        half8 Aev = {0, 0, 0, 0, 0, 0, 0, 0};
        half8 Aod = {0, 0, 0, 0, 0, 0, 0, 0};
        {
            float a0 = bp[row * 3 + 0], a1 = bp[row * 3 + 1], a2 = bp[row * 3 + 2];
            if (dir) { float t = 2.0f * (n0 * a0 + n1 * a1 + n2 * a2 + off); a0 -= t * n0; a1 -= t * n1; a2 -= t * n2; }
            if (lane < 32) {
                rsqbuf[rlocal] = a0 * a0 + a1 * a1 + a2 * a2;
                Aev[0] = (_Float16)a0; Aev[1] = (_Float16)a1;
                Aev[2] = (_Float16)a2; Aev[3] = (_Float16)1.0f;
                Aod[4] = (_Float16)a0; Aod[5] = (_Float16)a1;
                Aod[6] = (_Float16)a2; Aod[7] = (_Float16)1.0f;
            }
        }
        __syncthreads();

        // C fragment: rsq per output row (C/D: col=lane&31, row=(j&3)+8*(j>>2)+4*h)
        floatx16 crsq;
        #pragma unroll
        for (int j = 0; j < 16; ++j)
            crsq[j] = rsqbuf[wave * 32 + (j & 3) + 8 * (j >> 2) + 4 * h];

        float rm[16];
        #pragma unroll
        for (int j = 0; j < 16; ++j) rm[j] = 1e30f;

        // supertile u (64 cols): lane reads cols u*64 + {2l, 2l+1} as one b128
        const _Float16* bcol = &qcols[(lane & 31) * 8];
        #define LD(u) (*(const half8*)(bcol + (u) * 256))

        half8 c0 = LD(0), c1 = LD(1), c2 = LD(2), c3 = LD(3);
        floatx16 dA0, dA1, dB0, dB1;
        MFMA16(dA0, Aev, c0, crsq);  MFMA16(dA1, Aod, c0, crsq);   // st 0
        MFMA16(dB0, Aev, c1, crsq);  MFMA16(dB1, Aod, c1, crsq);   // st 1

        #pragma unroll 1
        for (int u = 4; u <= 60; u += 4) {
            c0 = LD(u);
            #pragma unroll
            for (int j = 0; j < 16; ++j) MIN3(rm[j], dA0[j], dA1[j]);   // st u-4
            MFMA16(dA0, Aev, c2, crsq);  MFMA16(dA1, Aod, c2, crsq);    // st u-2
            c1 = LD(u + 1);
            #pragma unroll
            for (int j = 0; j < 16; ++j) MIN3(rm[j], dB0[j], dB1[j]);   // st u-3
            MFMA16(dB0, Aev, c3, crsq);  MFMA16(dB1, Aod, c3, crsq);    // st u-1
            c2 = LD(u + 2);
            #pragma unroll
            for (int j = 0; j < 16; ++j) MIN3(rm[j], dA0[j], dA1[j]);   // st u-2
            MFMA16(dA0, Aev, c0, crsq);  MFMA16(dA1, Aod, c0, crsq);    // st u
            c3 = LD(u + 3);
            #pragma unroll
            for (int j = 0; j < 16; ++j) MIN3(rm[j], dB0[j], dB1[j]);   // st u-1
            MFMA16(dB0, Aev, c1, crsq);  MFMA16(dB1, Aod, c1, crsq);    // st u+1
        }
        {   // epilogue: st 62, 63 issue + drain (st 60..63 consumed here)
            #pragma unroll
            for (int j = 0; j < 16; ++j) MIN3(rm[j], dA0[j], dA1[j]);   // st 60
            MFMA16(dA0, Aev, c2, crsq);  MFMA16(dA1, Aod, c2, crsq);    // st 62
            #pragma unroll
            for (int j = 0; j < 16; ++j) MIN3(rm[j], dB0[j], dB1[j]);   // st 61
            MFMA16(dB0, Aev, c3, crsq);  MFMA16(dB1, Aod, c3, crsq);    // st 63
            #pragma unroll
            for (int j = 0; j < 16; ++j) MIN3(rm[j], dA0[j], dA1[j]);   // st 62
            #pragma unroll
            for (int j = 0; j < 16; ++j) MIN3(rm[j], dB0[j], dB1[j]);   // st 63
        }
        #undef LD

        // min across the 32 lanes sharing each row, then clamp + sum
        #pragma unroll
        for (int j = 0; j < 16; ++j) {
            float v = rm[j];
            v = fminf(v, __shfl_xor(v, 1));
            v = fminf(v, __shfl_xor(v, 2));
            v = fminf(v, __shfl_xor(v, 4));
            v = fminf(v, __shfl_xor(v, 8));
            v = fminf(v, __shfl_xor(v, 16));
            rm[j] = v;
        }
        float s = 0.0f;
        #pragma unroll
        for (int j = 0; j < 16; ++j) s += fmaxf(rm[j], 0.0f);  // clamp after min
        s += __shfl_xor(s, 32);   // combine the two 16-row halves of the wave
        total += s;

        __syncthreads();   // qcols/rsqbuf safe to overwrite for next dir
    }

    if (lane == 0) bsum[wave] = total;
    __syncthreads();
    if (tid == 0)
        atomicAdd(out, (bsum[0] + bsum[1] + bsum[2] + bsum[3]) * (1.0f / (float)(NB * NP)));
}

extern "C" void kernel_launch(void* const* d_in, const int* in_sizes, int n_in,
                              void* d_out, int out_size, void* d_ws, size_t ws_size,
                              hipStream_t stream) {
    const float* planes = (const float*)d_in[0];  // (8,3,4) fp32
    const float* pts    = (const float*)d_in[1];  // (8,4096,3) fp32
    float* out          = (float*)d_out;

    reg_kernel<<<1, 64, 0, stream>>>(planes, out);   // initializes out[0]

    dim3 grid(ROWBLKS, NBH);
    chamfer_mfma<<<grid, BLK, 0, stream>>>(pts, planes, out);
}